// Round 10
// baseline (49.906 us; speedup 1.0000x reference)
//
#include <hip/hip_runtime.h>

// SITH: out[t,o,f] = subset[o] * sum_n invL_sub[o,n] * ts[t,n,f]
//   ts[t,n,f] = d[n]*ts[t-1,n,f] + decay[n]*inp[t,f]
// invL_sub row o is EXACTLY banded: nonzero only n in [4o, 4o+8] (9 taps).
// State kept unscaled (p = d*p + x); decay*subset folded into taps.
//
// R10 vs R9:
//  - TC=16 / NC=32 (templated): 1280 pass-2 blocks -> ~5 waves/SIMD (was 2.5)
//    for latency hiding. Falls back to TC=32 if ws_size < 26 MB.
//  - plain stores (dropped nontemporal; fill kernel's 6.5 TB/s uses plain).

#define NF   512
#define NN   408
#define NO   100
#define TAPS 9
#define OPG  5      // outputs per o-group
#define NG   20     // o-groups (NG*OPG == NO)
#define ROWS 25     // state rows per o-group window [20g, 20g+24]
#define NPT  4      // n-rows per pass1 thread

// ---------------- Pass 1: chunk-boundary unscaled states ----------------
// thread = (n-quad, f); p = d*p + x, one x load feeds 4 single-FMA chains.
template<int TCP>
__global__ __launch_bounds__(256) void sith_pass1(
    const float* __restrict__ inp, const float* __restrict__ d,
    float* __restrict__ P)
{
    const int NBL = 512 / TCP - 1;                 // boundaries stored
    int gid = blockIdx.x * 256 + threadIdx.x;      // 102*512 threads
    int nq = gid >> 9;
    int f  = gid & (NF - 1);
    int n0 = nq * NPT;

    float dreg[NPT], st[NPT];
    #pragma unroll
    for (int q = 0; q < NPT; ++q) {
        dreg[q] = d[n0 + q];
        st[q] = 0.f;
    }

    const float* ip = inp + f;
    for (int b = 0; b < NBL; ++b) {
        #pragma unroll
        for (int tt = 0; tt < TCP; tt += 8) {
            float x[8];
            #pragma unroll
            for (int u = 0; u < 8; ++u)
                x[u] = ip[(b * TCP + tt + u) * NF];
            #pragma unroll
            for (int u = 0; u < 8; ++u) {
                #pragma unroll
                for (int q = 0; q < NPT; ++q)
                    st[q] = fmaf(dreg[q], st[q], x[u]);
            }
        }
        #pragma unroll
        for (int q = 0; q < NPT; ++q)
            P[b * (NN * NF) + (n0 + q) * NF + f] = st[q];
    }
}

// ---------------- Pass 2: per-chunk scan + banded projection ----------------
// block = (chunk c, o-chunk oc, f-slice fs). 256 threads = 4 waves.
// lane = f (64 consecutive), wave w -> o-group g = oc*4 + w (5 outputs).
template<int TCP>
__global__ __launch_bounds__(256) void sith_pass2(
    const float* __restrict__ inp, const float* __restrict__ invL,
    const float* __restrict__ d, const float* __restrict__ decay,
    const float* __restrict__ subset, const float* __restrict__ P,
    float* __restrict__ out)
{
    int bid = blockIdx.x;                 // (512/TCP) * 5 * 8
    int fs = bid & 7;
    int r  = bid >> 3;
    int oc = r % 5;
    int c  = r / 5;
    int tid = threadIdx.x;
    int lane = tid & 63;
    int w = tid >> 6;
    int g = oc * 4 + w;                   // 0..19
    int f = fs * 64 + lane;
    int nbase = NG * g;                   // row j -> n = nbase + j, j in [0,25)

    float dreg[ROWS], p[ROWS];
    #pragma unroll
    for (int j = 0; j < ROWS; ++j) {
        int n = nbase + j;                // <= 404 < 408: no guards
        dreg[j] = d[n];
        p[j] = (c == 0) ? 0.f : P[(c - 1) * (NN * NF) + n * NF + f];
    }

    float L[OPG][TAPS];
    #pragma unroll
    for (int k = 0; k < OPG; ++k) {
        int o = OPG * g + k;              // < 100 always
        float sub = subset[o];
        #pragma unroll
        for (int dd = 0; dd < TAPS; ++dd) {
            int n = nbase + 4 * k + dd;   // = 4o + dd, exact band
            L[k][dd] = invL[o * NN + n] * sub * decay[n];
        }
    }

    const float* ip = inp + f;
    int t0 = c * TCP;
    int obase = (t0 * NO + OPG * g) * NF + f;

#define SITH_STEP(xv)                                                      \
    {                                                                      \
        _Pragma("unroll")                                                  \
        for (int j = 0; j < ROWS; ++j)                                     \
            p[j] = fmaf(dreg[j], p[j], (xv));                              \
        _Pragma("unroll")                                                  \
        for (int k = 0; k < OPG; ++k) {                                    \
            float acc = 0.f;                                               \
            _Pragma("unroll")                                              \
            for (int dd = 0; dd < TAPS; ++dd)                              \
                acc = fmaf(L[k][dd], p[4 * k + dd], acc);                  \
            out[obase + k * NF] = acc;                                     \
        }                                                                  \
        obase += NO * NF;                                                  \
    }

    for (int tq = 0; tq < TCP; tq += 4) {
        float x0 = ip[(t0 + tq + 0) * NF];
        float x1 = ip[(t0 + tq + 1) * NF];
        float x2 = ip[(t0 + tq + 2) * NF];
        float x3 = ip[(t0 + tq + 3) * NF];
        SITH_STEP(x0);
        SITH_STEP(x1);
        SITH_STEP(x2);
        SITH_STEP(x3);
    }
#undef SITH_STEP
}

extern "C" void kernel_launch(void* const* d_in, const int* in_sizes, int n_in,
                              void* d_out, int out_size, void* d_ws, size_t ws_size,
                              hipStream_t stream)
{
    const float* inp    = (const float*)d_in[0];
    const float* invL   = (const float*)d_in[1];
    const float* d      = (const float*)d_in[2];
    const float* decay  = (const float*)d_in[3];
    const float* subset = (const float*)d_in[4];
    float* out = (float*)d_out;
    float* P   = (float*)d_ws;

    size_t need16 = (size_t)31 * NN * NF * 4;   // 25.9 MB for TC=16
    if (ws_size >= need16) {
        sith_pass1<16><<<(NN / NPT) * (NF / 256), 256, 0, stream>>>(inp, d, P);
        sith_pass2<16><<<32 * 5 * 8, 256, 0, stream>>>(inp, invL, d, decay, subset, P, out);
    } else {
        sith_pass1<32><<<(NN / NPT) * (NF / 256), 256, 0, stream>>>(inp, d, P);
        sith_pass2<32><<<16 * 5 * 8, 256, 0, stream>>>(inp, invL, d, decay, subset, P, out);
    }
}

// Round 11
// 39.057 us; speedup vs baseline: 1.2778x; 1.2778x over previous
//
#include <hip/hip_runtime.h>

// SITH: out[t,o,f] = subset[o] * sum_n invL_sub[o,n] * ts[t,n,f]
//   ts[t,n,f] = d[n]*ts[t-1,n,f] + decay[n]*inp[t,f]
// invL_sub row o is EXACTLY banded: nonzero only n in [4o, 4o+8] (9 taps).
// State unscaled (p = d*p + x); decay*subset folded into taps.
//
// R11 vs R9:
//  - XCD-pinned P: both passes partition f into 8 slices of 64 and put
//    f-slice fs on XCD fs (bid%8 == fs in both kernels; 40%8==0 keeps it
//    true for all chunks). P per slice = 1.6 MB -> stays in that XCD's L2.
//  - pass2: rotated x-prefetch (next 4-group loaded before current steps),
//    masked t index so no bounds branch.
//  - 2D grids, no div/mod in block decode.

#define NF   512
#define NN   408
#define NO   100
#define NC   16     // time chunks
#define TC   32     // steps per chunk
#define NB   15     // boundary states stored (chunks 0..14)
#define TAPS 9
#define OPG  5      // outputs per o-group
#define NG   20     // o-groups (NG*OPG == NO)
#define ROWS 25     // state rows per o-group window [20g, 20g+24]
#define NPT  4      // n-rows per pass1 thread

// ---------------- Pass 1: chunk-boundary unscaled states ----------------
// grid (8, 26): x = f-slice (XCD), y = 16-row band. 256 thr = 64 f x 4 row-quads.
__global__ __launch_bounds__(256) void sith_pass1(
    const float* __restrict__ inp, const float* __restrict__ d,
    float* __restrict__ P)
{
    int fs = blockIdx.x;                  // 0..7  == XCD
    int a  = blockIdx.y;                  // 0..25
    int tid = threadIdx.x;
    int lane = tid & 63;
    int y = tid >> 6;                     // 0..3
    int n0 = a * 16 + y * NPT;            // 0..412, multiple of 4
    if (n0 >= NN) return;                 // a=25, y>=2
    int f = fs * 64 + lane;

    float dreg[NPT], st[NPT];
    #pragma unroll
    for (int q = 0; q < NPT; ++q) {
        dreg[q] = d[n0 + q];
        st[q] = 0.f;
    }

    const float* ip = inp + f;
    for (int b = 0; b < NB; ++b) {        // last chunk never stored
        #pragma unroll
        for (int tt = 0; tt < TC; tt += 8) {
            float x[8];
            #pragma unroll
            for (int u = 0; u < 8; ++u)
                x[u] = ip[(b * TC + tt + u) * NF];
            #pragma unroll
            for (int u = 0; u < 8; ++u) {
                #pragma unroll
                for (int q = 0; q < NPT; ++q)
                    st[q] = fmaf(dreg[q], st[q], x[u]);
            }
        }
        #pragma unroll
        for (int q = 0; q < NPT; ++q)
            P[b * (NN * NF) + (n0 + q) * NF + f] = st[q];
    }
}

// ---------------- Pass 2: per-chunk scan + banded projection ----------------
// grid (40, 16): x = oc*8 + fs (fs = bid%8 = XCD), y = chunk c.
// 256 thr = 4 waves; lane = f (64 consecutive), wave w -> g = oc*4 + w.
__global__ __launch_bounds__(256) void sith_pass2(
    const float* __restrict__ inp, const float* __restrict__ invL,
    const float* __restrict__ d, const float* __restrict__ decay,
    const float* __restrict__ subset, const float* __restrict__ P,
    float* __restrict__ out)
{
    int bx = blockIdx.x;                  // 0..39
    int fs = bx & 7;
    int oc = bx >> 3;                     // 0..4
    int c  = blockIdx.y;                  // 0..15
    int tid = threadIdx.x;
    int lane = tid & 63;
    int w = tid >> 6;
    int g = oc * 4 + w;                   // 0..19
    int f = fs * 64 + lane;
    int nbase = NG * g;                   // row j -> n = nbase + j, j in [0,25)

    float dreg[ROWS], p[ROWS];
    #pragma unroll
    for (int j = 0; j < ROWS; ++j) {
        int n = nbase + j;                // <= 404 < 408: no guards
        dreg[j] = d[n];
        p[j] = (c == 0) ? 0.f : P[(c - 1) * (NN * NF) + n * NF + f];
    }

    float L[OPG][TAPS];
    #pragma unroll
    for (int k = 0; k < OPG; ++k) {
        int o = OPG * g + k;              // < 100 always
        float sub = subset[o];
        #pragma unroll
        for (int dd = 0; dd < TAPS; ++dd) {
            int n = nbase + 4 * k + dd;   // = 4o + dd, exact band
            L[k][dd] = invL[o * NN + n] * sub * decay[n];
        }
    }

    const float* ip = inp + f;
    int t0 = c * TC;
    int obase = (t0 * NO + OPG * g) * NF + f;

#define SITH_STEP(xv)                                                      \
    {                                                                      \
        _Pragma("unroll")                                                  \
        for (int j = 0; j < ROWS; ++j)                                     \
            p[j] = fmaf(dreg[j], p[j], (xv));                              \
        _Pragma("unroll")                                                  \
        for (int k = 0; k < OPG; ++k) {                                    \
            float acc = 0.f;                                               \
            _Pragma("unroll")                                              \
            for (int dd = 0; dd < TAPS; ++dd)                              \
                acc = fmaf(L[k][dd], p[4 * k + dd], acc);                  \
            __builtin_nontemporal_store(acc, &out[obase + k * NF]);        \
        }                                                                  \
        obase += NO * NF;                                                  \
    }

    // rotated prefetch: next 4-group's x loads issue before current steps.
    float xb0 = ip[(t0 + 0) * NF];
    float xb1 = ip[(t0 + 1) * NF];
    float xb2 = ip[(t0 + 2) * NF];
    float xb3 = ip[(t0 + 3) * NF];

    for (int tq = 0; tq < TC; tq += 4) {
        // masked index: last group's prefetch wraps into [0,512) (unused)
        int tp = t0 + tq + 4;
        float xn0 = ip[((tp + 0) & 511) * NF];
        float xn1 = ip[((tp + 1) & 511) * NF];
        float xn2 = ip[((tp + 2) & 511) * NF];
        float xn3 = ip[((tp + 3) & 511) * NF];
        SITH_STEP(xb0);
        SITH_STEP(xb1);
        SITH_STEP(xb2);
        SITH_STEP(xb3);
        xb0 = xn0; xb1 = xn1; xb2 = xn2; xb3 = xn3;
    }
#undef SITH_STEP
}

extern "C" void kernel_launch(void* const* d_in, const int* in_sizes, int n_in,
                              void* d_out, int out_size, void* d_ws, size_t ws_size,
                              hipStream_t stream)
{
    const float* inp    = (const float*)d_in[0];
    const float* invL   = (const float*)d_in[1];
    const float* d      = (const float*)d_in[2];
    const float* decay  = (const float*)d_in[3];
    const float* subset = (const float*)d_in[4];
    float* out = (float*)d_out;
    float* P   = (float*)d_ws;   // 15 * 408 * 512 * 4 B = 12.5 MB boundary states

    sith_pass1<<<dim3(8, 26), 256, 0, stream>>>(inp, d, P);
    sith_pass2<<<dim3(40, NC), 256, 0, stream>>>(inp, invL, d, decay, subset, P, out);
}